// Round 11
// baseline (924.703 us; speedup 1.0000x reference)
//
#include <hip/hip_runtime.h>
#include <math.h>

#define BATCH 8
#define CH 128
#define NPTS 65536
#define NBLKA 16          // blocks per batch in phase A (4096 pts/block, 512 threads, 8 pts/thread)
#define APTS 4096
#define NBLKB 32          // blocks per batch in phase B (2048 pts/block)
#define BPTS 2048
#define PB_STRIDE 260     // 2*CH sums + 2 counts + pad (doubles)

typedef float fvec4 __attribute__((ext_vector_type(4)));

// ---- workspace byte offsets ----
// centers: two ping-pong slots [2][B][2][CH] f32 (slot = t&1, written by phaseA<t> blk0)
static constexpr size_t WS_CENTERS = 0;
static constexpr size_t WS_CINI    = WS_CENTERS + (size_t)2 * BATCH * 2 * CH * sizeof(float); // [B][2] f32
static constexpr size_t WS_PA      = WS_CINI + 256;                                           // [B][NBLKA][4] f64
static constexpr size_t WS_PMM     = WS_PA + (size_t)BATCH * NBLKA * 4 * sizeof(double);      // [B][NBLKA][4] f32
static constexpr size_t WS_PB      = WS_PMM + (size_t)BATCH * NBLKA * 4 * sizeof(float);      // [B][NBLKB][260] f64

// ---- output float offsets (reference return order) ----
static constexpr size_t OUT_CITER  = 0;                                     // [2][CH]
static constexpr size_t OUT_LABELS = 256;                                   // [B][N]
static constexpr size_t OUT_ONEHOT = OUT_LABELS + (size_t)BATCH * NPTS;     // [B][N][2]
static constexpr size_t OUT_WEIGHT = OUT_ONEHOT + (size_t)BATCH * NPTS * 2; // [B][N][2]
static constexpr size_t OUT_DISTS  = OUT_WEIGHT + (size_t)BATCH * NPTS * 2; // [B][N][2] (scratch each iter; final iter = output)
static constexpr size_t OUT_LABELP = OUT_DISTS + (size_t)BATCH * NPTS * 2;  // [B][N]
static constexpr size_t OUT_CINID  = OUT_LABELP + (size_t)BATCH * NPTS;     // scalar

// Phase A (iteration T=0..5): prolog derives centers(T) (T>=1: redundant reduceB fold),
// then computes dists + threshold partial sums. T==1 writes labelPinit; T==5 writes
// labels/onehot + min/max partials.
// 512 threads x 8 pts: 16 KB contiguous per channel visit (DRAM row locality), 128 blocks.
// X loads are NON-TEMPORAL (zero reuse; bit-identical values).
// NOTE: the per-point channel loop MUST stay sequential c=0..127 — per-point accumulation
// order is part of the numerical contract (argmin label flips otherwise; round-6 lesson).
template <int T>
__global__ __launch_bounds__(512) void phaseA_k(const float* __restrict__ X,
                                                const float* __restrict__ cinit,
                                                char* __restrict__ ws,
                                                float* __restrict__ out) {
    const int b = blockIdx.x / NBLKA;
    const int blk = blockIdx.x % NBLKA;
    const int tid = threadIdx.x;
    const int wid = tid >> 6, lane = tid & 63;   // 8 waves

    __shared__ float cn[2][CH];
    __shared__ double redd[3][8];
    __shared__ float redmm[4][8];

    if constexpr (T == 0) {
        // centers(0) = cinit (same for every batch); normalize into LDS
        if (wid < 2) {
            float v0 = cinit[wid * CH + lane];
            float v1 = cinit[wid * CH + lane + 64];
            float ssq = v0 * v0 + v1 * v1;
#pragma unroll
            for (int o = 32; o > 0; o >>= 1) ssq += __shfl_down(ssq, o);
            ssq = __shfl(ssq, 0);
            const float inv = 1.0f / fmaxf(sqrtf(ssq), 1e-12f);
            cn[wid][lane] = v0 * inv;
            cn[wid][lane + 64] = v1 * inv;
        }
    } else {
        // ---- folded reduceB(T-1): pB partials -> centersIter(T-1) -> EMA -> centers(T) ----
        __shared__ float cnt_s[2];
        __shared__ float red4[4];
        const double* pB = (const double*)(ws + WS_PB) + (size_t)b * NBLKB * PB_STRIDE;
        if (tid < 64) {   // counts: lanes 0..31 -> j=0, 32..63 -> j=1
            const int jj = tid >> 5, kb = tid & 31;
            double v = pB[(size_t)kb * PB_STRIDE + 2 * CH + jj];
#pragma unroll
            for (int o = 16; o > 0; o >>= 1) v += __shfl_down(v, o);
            if ((tid & 31) == 0) cnt_s[jj] = (float)v;
        }
        const int j = tid >> 7, c = tid & (CH - 1);
        double s = 0.0;
        if (tid < 256) {
            for (int kb = 0; kb < NBLKB; ++kb) s += pB[(size_t)kb * PB_STRIDE + j * CH + c];
        }
        __syncthreads();
        float ci = 0.f, old = 0.f, cnew = 0.f;
        if (tid < 256) {
            ci = (float)s / (cnt_s[j] + 1.0f);
            old = (T == 1)
                ? cinit[tid]
                : ((const float*)(ws + WS_CENTERS))[(size_t)((T - 1) & 1) * BATCH * 2 * CH + b * 2 * CH + tid];
            cnew = old + 0.1f * (ci - old);
            float ss = cnew * cnew;
#pragma unroll
            for (int o = 32; o > 0; o >>= 1) ss += __shfl_down(ss, o);
            if (lane == 0) red4[wid] = ss;   // waves 0..3
        }
        __syncthreads();
        if (tid < 256) {
            const float nrm = sqrtf(red4[j * 2] + red4[j * 2 + 1]);
            cn[j][c] = cnew / fmaxf(nrm, 1e-12f);
        }
        if constexpr (T == 1) {
            // cinidist: cos_sim(centersIter(0), centers(0)) rows
            __shared__ float rsd[4], rsa[4], rsb[4];
            if (tid < 256) {
                float sd = ci * old, sa = ci * ci, sb = old * old;
#pragma unroll
                for (int o = 32; o > 0; o >>= 1) {
                    sd += __shfl_down(sd, o); sa += __shfl_down(sa, o); sb += __shfl_down(sb, o);
                }
                if (lane == 0) { rsd[wid] = sd; rsa[wid] = sa; rsb[wid] = sb; }
            }
            __syncthreads();
            if (blk == 0 && tid < 2) {
                const float nsd = rsd[tid * 2] + rsd[tid * 2 + 1];
                const float nsa = rsa[tid * 2] + rsa[tid * 2 + 1];
                const float nsb = rsb[tid * 2] + rsb[tid * 2 + 1];
                ((float*)(ws + WS_CINI))[b * 2 + tid] = nsd / fmaxf(sqrtf(nsa) * sqrtf(nsb), 1e-8f);
            }
        }
        if (blk == 0 && tid < 256) {   // persist centers(T) for phaseA<T+1>
            ((float*)(ws + WS_CENTERS))[(size_t)(T & 1) * BATCH * 2 * CH + b * 2 * CH + tid] = cnew;
        }
    }
    __syncthreads();

    // ---- streaming pass: dists + partial sums (sequential c — DO NOT reorder) ----
    const int n0 = blk * APTS + tid * 8;
    const float* Xb = X + (size_t)b * CH * NPTS + n0;
    fvec4 a0[2], a1[2], aq[2];
#pragma unroll
    for (int h = 0; h < 2; ++h) { a0[h] = (fvec4)0.f; a1[h] = (fvec4)0.f; aq[h] = (fvec4)0.f; }
#pragma unroll 8
    for (int c = 0; c < CH; ++c) {
        const fvec4 x0 = __builtin_nontemporal_load((const fvec4*)(Xb + (size_t)c * NPTS));
        const fvec4 x1 = __builtin_nontemporal_load((const fvec4*)(Xb + (size_t)c * NPTS + 4));
        const float w0 = cn[0][c], w1 = cn[1][c];
        a0[0] += x0 * w0; a1[0] += x0 * w1; aq[0] += x0 * x0;
        a0[1] += x1 * w0; a1[1] += x1 * w1; aq[1] += x1 * x1;
    }

    float2* distsb = (float2*)(out + OUT_DISTS) + (size_t)b * NPTS;
    double sLf = 0.0, sD0 = 0.0, sD1 = 0.0;
    float mn0 = 1e30f, mx0 = -1e30f, mn1 = 1e30f, mx1 = -1e30f;

#pragma unroll
    for (int h = 0; h < 2; ++h) {
#pragma unroll
        for (int k = 0; k < 4; ++k) {
            const int n = n0 + h * 4 + k;
            const float invn = 1.0f / fmaxf(sqrtf(aq[h][k]), 1e-12f);
            const float d0 = 0.5f * (1.0f - a0[h][k] * invn);
            const float d1 = 0.5f * (1.0f - a1[h][k] * invn);
            const int lab = d1 < d0;
            distsb[n] = make_float2(d0, d1);
            sLf += (double)lab;
            sD0 += lab ? 0.0 : (double)d0;
            sD1 += lab ? (double)d1 : 0.0;
            if (T == 1) {
                out[OUT_LABELP + (size_t)b * NPTS + n] = (float)lab;
            }
            if (T == 5) {
                const size_t pn = (size_t)b * NPTS + n;
                out[OUT_LABELS + pn] = (float)lab;
                *(float2*)(out + OUT_ONEHOT + pn * 2) = make_float2(lab ? 0.0f : 1.0f, lab ? 1.0f : 0.0f);
                mn0 = fminf(mn0, d0); mx0 = fmaxf(mx0, d0);
                mn1 = fminf(mn1, d1); mx1 = fmaxf(mx1, d1);
            }
        }
    }

#pragma unroll
    for (int o = 32; o > 0; o >>= 1) {
        sLf += __shfl_down(sLf, o);
        sD0 += __shfl_down(sD0, o);
        sD1 += __shfl_down(sD1, o);
    }
    if (lane == 0) { redd[0][wid] = sLf; redd[1][wid] = sD0; redd[2][wid] = sD1; }
    if (T == 5) {
#pragma unroll
        for (int o = 32; o > 0; o >>= 1) {
            mn0 = fminf(mn0, __shfl_down(mn0, o));
            mx0 = fmaxf(mx0, __shfl_down(mx0, o));
            mn1 = fminf(mn1, __shfl_down(mn1, o));
            mx1 = fmaxf(mx1, __shfl_down(mx1, o));
        }
        if (lane == 0) { redmm[0][wid] = mn0; redmm[1][wid] = mx0; redmm[2][wid] = mn1; redmm[3][wid] = mx1; }
    }
    __syncthreads();
    if (tid == 0) {
        double* pA = (double*)(ws + WS_PA) + (size_t)(b * NBLKA + blk) * 4;
        double t0 = 0, t1 = 0, t2 = 0;
#pragma unroll
        for (int w = 0; w < 8; ++w) { t0 += redd[0][w]; t1 += redd[1][w]; t2 += redd[2][w]; }
        pA[0] = t0; pA[1] = t1; pA[2] = t2;
        if (T == 5) {
            float* pMM = (float*)(ws + WS_PMM) + (size_t)(b * NBLKA + blk) * 4;
            float m0 = 1e30f, m1 = -1e30f, m2 = 1e30f, m3 = -1e30f;
#pragma unroll
            for (int w = 0; w < 8; ++w) {
                m0 = fminf(m0, redmm[0][w]); m1 = fmaxf(m1, redmm[1][w]);
                m2 = fminf(m2, redmm[2][w]); m3 = fmaxf(m3, redmm[3][w]);
            }
            pMM[0] = m0; pMM[1] = m1; pMM[2] = m2; pMM[3] = m3;
        }
    }
}

// Phase B (iteration T): prolog folds reduceA (thresholds) [+ min/max reduce at T==5],
// then flag build (+ Weight output at T==5) and flag-weighted per-channel sums.
// Phase B decomposition/accumulation is part of the numerical contract — DO NOT change.
// X loads non-temporal (bit-identical values).
template <int T>
__global__ __launch_bounds__(512) void phaseB_k(const float* __restrict__ X,
                                                char* __restrict__ ws,
                                                float* __restrict__ out,
                                                const int* __restrict__ n1p,
                                                const int* __restrict__ n2p) {
    const int b = blockIdx.x / NBLKB, blk = blockIdx.x % NBLKB;
    const int tid = threadIdx.x, wid = tid >> 6, lane = tid & 63;
    const int base = blk * BPTS;

    __shared__ float flgC[BPTS];
    __shared__ float flgU[BPTS];
    __shared__ double redc[2][8];
    __shared__ float thr_s[2];
    __shared__ float mm[4];

    // ---- folded reduceA: thresholds from pA partials (NBLKA per batch) ----
    if (wid == 0) {
        const double* pA = (const double*)(ws + WS_PA) + (size_t)b * NBLKA * 4;
        double sLf = 0.0, sD0 = 0.0, sD1 = 0.0;
        if (lane < NBLKA) {
            sLf = pA[lane * 4 + 0]; sD0 = pA[lane * 4 + 1]; sD1 = pA[lane * 4 + 2];
        }
#pragma unroll
        for (int o = 32; o > 0; o >>= 1) {
            sLf += __shfl_down(sLf, o);
            sD0 += __shfl_down(sD0, o);
            sD1 += __shfl_down(sD1, o);
        }
        if (lane == 0) {
            const float fn1 = (float)(*n1p), fn2 = (float)(*n2p);
            const double chgNum = sLf + 1.0;
            const double unchgNum = ((double)NPTS - sLf) + 1.0;
            thr_s[0] = (float)(sD0 / unchgNum) * fn2;   // unchg threshold
            thr_s[1] = (float)(sD1 / chgNum) / fn1;     // chg threshold
        }
    }
    if (T == 5 && wid == 1) {   // global min/max for Weight
        const float* pMM = (const float*)(ws + WS_PMM) + (size_t)b * NBLKA * 4;
        float mn0 = 1e30f, mx0 = -1e30f, mn1 = 1e30f, mx1 = -1e30f;
        if (lane < NBLKA) {
            const float4 v = *(const float4*)(pMM + lane * 4);
            mn0 = v.x; mx0 = v.y; mn1 = v.z; mx1 = v.w;
        }
#pragma unroll
        for (int o = 32; o > 0; o >>= 1) {
            mn0 = fminf(mn0, __shfl_down(mn0, o)); mx0 = fmaxf(mx0, __shfl_down(mx0, o));
            mn1 = fminf(mn1, __shfl_down(mn1, o)); mx1 = fmaxf(mx1, __shfl_down(mx1, o));
        }
        if (lane == 0) { mm[0] = mn0; mm[1] = mx0; mm[2] = mn1; mm[3] = mx1; }
    }
    __syncthreads();

    const float unchgT = thr_s[0], chgT = thr_s[1];
    const float2* distsb = (const float2*)(out + OUT_DISTS) + (size_t)b * NPTS + base;

    float cc = 0.f, cu = 0.f;
#pragma unroll
    for (int i = 0; i < BPTS / 512; ++i) {
        const int nl = tid + 512 * i;
        const float2 d = distsb[nl];
        const int lab = d.y < d.x;
        const float fc = (lab && d.y <= chgT) ? 1.f : 0.f;
        const float fu = (!lab && d.x <= unchgT) ? 1.f : 0.f;
        flgC[nl] = fc;
        flgU[nl] = fu;
        cc += fc; cu += fu;
        if (T == 5) {   // fold Weight output into this read of dists
            const float den0 = mm[1] - mm[0] + 1e-7f;
            const float den1 = mm[3] - mm[2] + 1e-7f;
            float* wout = out + OUT_WEIGHT + ((size_t)b * NPTS + base + nl) * 2;
            *(float2*)wout = make_float2(1.0f - (d.x - mm[0]) / den0,
                                         1.0f - (d.y - mm[2]) / den1);
        }
    }
    double dcc = (double)cc, dcu = (double)cu;
#pragma unroll
    for (int o = 32; o > 0; o >>= 1) {
        dcc += __shfl_down(dcc, o);
        dcu += __shfl_down(dcu, o);
    }
    if (lane == 0) { redc[0][wid] = dcu; redc[1][wid] = dcc; }
    __syncthreads();

    double* pB = (double*)(ws + WS_PB) + (size_t)(b * NBLKB + blk) * PB_STRIDE;
    if (tid == 0) {
        double tu = 0, tc = 0;
#pragma unroll
        for (int w = 0; w < 8; ++w) { tu += redc[0][w]; tc += redc[1][w]; }
        pB[2 * CH + 0] = tu;
        pB[2 * CH + 1] = tc;
    }

    const float* Xb = X + (size_t)b * CH * NPTS + base;
    for (int c0 = CH / 8 - 1; c0 >= 0; --c0) {   // 16 channels per wave, DESCENDING
        const int c = wid * (CH / 8) + c0;
        const float* Xc = Xb + (size_t)c * NPTS;
        float aC = 0.f, aU = 0.f;
#pragma unroll
        for (int it = 0; it < BPTS / 256; ++it) {
            const int idx = it * 256 + lane * 4;
            const fvec4 x = __builtin_nontemporal_load((const fvec4*)(Xc + idx));
            const float4 fc = *(const float4*)(&flgC[idx]);
            const float4 fu = *(const float4*)(&flgU[idx]);
            aC += x.x * fc.x + x.y * fc.y + x.z * fc.z + x.w * fc.w;
            aU += x.x * fu.x + x.y * fu.y + x.z * fu.z + x.w * fu.w;
        }
#pragma unroll
        for (int o = 32; o > 0; o >>= 1) {
            aC += __shfl_down(aC, o);
            aU += __shfl_down(aU, o);
        }
        if (lane == 0) {
            pB[0 * CH + c] = (double)aU;   // row 0 = unchg
            pB[1 * CH + c] = (double)aC;   // row 1 = chg
        }
    }
}

// Final tiny kernel: centersIterout (mean over batches of reduceB(5)) + Cinidist
__global__ __launch_bounds__(256) void finalK(char* __restrict__ ws, float* __restrict__ out) {
    const int tid = threadIdx.x;
    __shared__ float cnt_s[BATCH][2];
    const double* pB0 = (const double*)(ws + WS_PB);
    if (tid < 16) {
        const int bb = tid >> 1, jj = tid & 1;
        double v = 0.0;
        for (int kb = 0; kb < NBLKB; ++kb)
            v += pB0[(size_t)bb * NBLKB * PB_STRIDE + (size_t)kb * PB_STRIDE + 2 * CH + jj];
        cnt_s[bb][jj] = (float)v;
    }
    __syncthreads();
    const int j = tid >> 7;
    double acc = 0.0;
    for (int bb = 0; bb < BATCH; ++bb) {
        double s = 0.0;
        for (int kb = 0; kb < NBLKB; ++kb)
            s += pB0[(size_t)bb * NBLKB * PB_STRIDE + (size_t)kb * PB_STRIDE + tid];
        acc += (double)((float)s / (cnt_s[bb][j] + 1.0f));
    }
    out[OUT_CITER + tid] = (float)(acc / (double)BATCH);
    if (tid == 0) {
        const float* cini = (const float*)(ws + WS_CINI);
        out[OUT_CINID] = (cini[(BATCH - 1) * 2 + 0] + cini[(BATCH - 1) * 2 + 1]) / (float)BATCH;
    }
}

extern "C" void kernel_launch(void* const* d_in, const int* in_sizes, int n_in,
                              void* d_out, int out_size, void* d_ws, size_t ws_size,
                              hipStream_t stream) {
    const float* X = (const float*)d_in[0];       // [8,128,256,256] f32
    const float* cinit = (const float*)d_in[1];   // [2,128] f32
    const int* num1 = (const int*)d_in[2];
    const int* num2 = (const int*)d_in[3];
    float* out = (float*)d_out;
    char* ws = (char*)d_ws;

    const dim3 gA(BATCH * NBLKA), bA(512);
    const dim3 gB(BATCH * NBLKB), bB(512);

    phaseA_k<0><<<gA, bA, 0, stream>>>(X, cinit, ws, out);
    phaseB_k<0><<<gB, bB, 0, stream>>>(X, ws, out, num1, num2);
    phaseA_k<1><<<gA, bA, 0, stream>>>(X, cinit, ws, out);
    phaseB_k<1><<<gB, bB, 0, stream>>>(X, ws, out, num1, num2);
    phaseA_k<2><<<gA, bA, 0, stream>>>(X, cinit, ws, out);
    phaseB_k<2><<<gB, bB, 0, stream>>>(X, ws, out, num1, num2);
    phaseA_k<3><<<gA, bA, 0, stream>>>(X, cinit, ws, out);
    phaseB_k<3><<<gB, bB, 0, stream>>>(X, ws, out, num1, num2);
    phaseA_k<4><<<gA, bA, 0, stream>>>(X, cinit, ws, out);
    phaseB_k<4><<<gB, bB, 0, stream>>>(X, ws, out, num1, num2);
    phaseA_k<5><<<gA, bA, 0, stream>>>(X, cinit, ws, out);
    phaseB_k<5><<<gB, bB, 0, stream>>>(X, ws, out, num1, num2);
    finalK<<<1, 256, 0, stream>>>(ws, out);
}

// Round 12
// 574.787 us; speedup vs baseline: 1.6088x; 1.6088x over previous
//
#include <hip/hip_runtime.h>
#include <math.h>

#define BATCH 8
#define CH 128
#define NPTS 65536
#define NBLKA 32          // blocks per batch in phase A (2048 pts/block, 512 threads, 4 pts/thread)
#define APTS 2048
#define NBLKB 32          // blocks per batch in phase B (2048 pts/block)
#define BPTS 2048
#define PB_STRIDE 260     // 2*CH sums + 2 counts + pad (doubles)

typedef float fvec4 __attribute__((ext_vector_type(4)));

// ---- workspace byte offsets ----
// centers: two ping-pong slots [2][B][2][CH] f32 (slot = t&1, written by phaseA<t> blk0)
static constexpr size_t WS_CENTERS = 0;
static constexpr size_t WS_CINI    = WS_CENTERS + (size_t)2 * BATCH * 2 * CH * sizeof(float); // [B][2] f32
static constexpr size_t WS_PA      = WS_CINI + 256;                                           // [B][NBLKA][4] f64
static constexpr size_t WS_PMM     = WS_PA + (size_t)BATCH * NBLKA * 4 * sizeof(double);      // [B][NBLKA][4] f32
static constexpr size_t WS_PB      = WS_PMM + (size_t)BATCH * NBLKA * 4 * sizeof(float);      // [B][NBLKB][260] f64

// ---- output float offsets (reference return order) ----
static constexpr size_t OUT_CITER  = 0;                                     // [2][CH]
static constexpr size_t OUT_LABELS = 256;                                   // [B][N]
static constexpr size_t OUT_ONEHOT = OUT_LABELS + (size_t)BATCH * NPTS;     // [B][N][2]
static constexpr size_t OUT_WEIGHT = OUT_ONEHOT + (size_t)BATCH * NPTS * 2; // [B][N][2]
static constexpr size_t OUT_DISTS  = OUT_WEIGHT + (size_t)BATCH * NPTS * 2; // [B][N][2] (scratch each iter; final iter = output)
static constexpr size_t OUT_LABELP = OUT_DISTS + (size_t)BATCH * NPTS * 2;  // [B][N]
static constexpr size_t OUT_CINID  = OUT_LABELP + (size_t)BATCH * NPTS;     // scalar

// Phase A (iteration T=0..5): prolog derives centers(T) (T>=1: redundant reduceB fold),
// then computes dists + threshold partial sums. T==1 writes labelPinit; T==5 writes
// labels/onehot + min/max partials.
// Geometry: 256 blocks (1/CU — NEVER fewer than 256 blocks; round-11 lesson: 128 blocks
// left half the GPU idle, +65 us/pass). 512 threads x 4 pts = 8 KB contiguous per
// channel visit (round-10 verified win). X loads NON-TEMPORAL (bit-identical values;
// X has zero reuse, keeps L3 free for the reused dists buffer) — this round's single variable.
// NOTE: the per-point channel loop MUST stay sequential c=0..127 — per-point accumulation
// order is part of the numerical contract (argmin label flips otherwise; round-6 lesson).
template <int T>
__global__ __launch_bounds__(512) void phaseA_k(const float* __restrict__ X,
                                                const float* __restrict__ cinit,
                                                char* __restrict__ ws,
                                                float* __restrict__ out) {
    const int b = blockIdx.x / NBLKA;
    const int blk = blockIdx.x % NBLKA;
    const int tid = threadIdx.x;
    const int wid = tid >> 6, lane = tid & 63;   // 8 waves

    __shared__ float cn[2][CH];
    __shared__ double redd[3][8];
    __shared__ float redmm[4][8];

    if constexpr (T == 0) {
        // centers(0) = cinit (same for every batch); normalize into LDS
        if (wid < 2) {
            float v0 = cinit[wid * CH + lane];
            float v1 = cinit[wid * CH + lane + 64];
            float ssq = v0 * v0 + v1 * v1;
#pragma unroll
            for (int o = 32; o > 0; o >>= 1) ssq += __shfl_down(ssq, o);
            ssq = __shfl(ssq, 0);
            const float inv = 1.0f / fmaxf(sqrtf(ssq), 1e-12f);
            cn[wid][lane] = v0 * inv;
            cn[wid][lane + 64] = v1 * inv;
        }
    } else {
        // ---- folded reduceB(T-1): pB partials -> centersIter(T-1) -> EMA -> centers(T) ----
        __shared__ float cnt_s[2];
        __shared__ float red4[4];
        const double* pB = (const double*)(ws + WS_PB) + (size_t)b * NBLKB * PB_STRIDE;
        if (tid < 64) {   // counts: lanes 0..31 -> j=0, 32..63 -> j=1
            const int jj = tid >> 5, kb = tid & 31;
            double v = pB[(size_t)kb * PB_STRIDE + 2 * CH + jj];
#pragma unroll
            for (int o = 16; o > 0; o >>= 1) v += __shfl_down(v, o);
            if ((tid & 31) == 0) cnt_s[jj] = (float)v;
        }
        const int j = tid >> 7, c = tid & (CH - 1);
        double s = 0.0;
        if (tid < 256) {
            for (int kb = 0; kb < NBLKB; ++kb) s += pB[(size_t)kb * PB_STRIDE + j * CH + c];
        }
        __syncthreads();
        float ci = 0.f, old = 0.f, cnew = 0.f;
        if (tid < 256) {
            ci = (float)s / (cnt_s[j] + 1.0f);
            old = (T == 1)
                ? cinit[tid]
                : ((const float*)(ws + WS_CENTERS))[(size_t)((T - 1) & 1) * BATCH * 2 * CH + b * 2 * CH + tid];
            cnew = old + 0.1f * (ci - old);
            float ss = cnew * cnew;
#pragma unroll
            for (int o = 32; o > 0; o >>= 1) ss += __shfl_down(ss, o);
            if (lane == 0) red4[wid] = ss;   // waves 0..3
        }
        __syncthreads();
        if (tid < 256) {
            const float nrm = sqrtf(red4[j * 2] + red4[j * 2 + 1]);
            cn[j][c] = cnew / fmaxf(nrm, 1e-12f);
        }
        if constexpr (T == 1) {
            // cinidist: cos_sim(centersIter(0), centers(0)) rows
            __shared__ float rsd[4], rsa[4], rsb[4];
            if (tid < 256) {
                float sd = ci * old, sa = ci * ci, sb = old * old;
#pragma unroll
                for (int o = 32; o > 0; o >>= 1) {
                    sd += __shfl_down(sd, o); sa += __shfl_down(sa, o); sb += __shfl_down(sb, o);
                }
                if (lane == 0) { rsd[wid] = sd; rsa[wid] = sa; rsb[wid] = sb; }
            }
            __syncthreads();
            if (blk == 0 && tid < 2) {
                const float nsd = rsd[tid * 2] + rsd[tid * 2 + 1];
                const float nsa = rsa[tid * 2] + rsa[tid * 2 + 1];
                const float nsb = rsb[tid * 2] + rsb[tid * 2 + 1];
                ((float*)(ws + WS_CINI))[b * 2 + tid] = nsd / fmaxf(sqrtf(nsa) * sqrtf(nsb), 1e-8f);
            }
        }
        if (blk == 0 && tid < 256) {   // persist centers(T) for phaseA<T+1>
            ((float*)(ws + WS_CENTERS))[(size_t)(T & 1) * BATCH * 2 * CH + b * 2 * CH + tid] = cnew;
        }
    }
    __syncthreads();

    // ---- streaming pass: dists + partial sums (sequential c — DO NOT reorder) ----
    const int n0 = blk * APTS + tid * 4;
    const float* Xb = X + (size_t)b * CH * NPTS + n0;
    fvec4 a0 = (fvec4)0.f, a1 = (fvec4)0.f, aq = (fvec4)0.f;
#pragma unroll 8
    for (int c = 0; c < CH; ++c) {
        const fvec4 x = __builtin_nontemporal_load((const fvec4*)(Xb + (size_t)c * NPTS));
        const float w0 = cn[0][c], w1 = cn[1][c];
        a0 += x * w0;
        a1 += x * w1;
        aq += x * x;
    }

    float2* distsb = (float2*)(out + OUT_DISTS) + (size_t)b * NPTS;
    double sLf = 0.0, sD0 = 0.0, sD1 = 0.0;
    float mn0 = 1e30f, mx0 = -1e30f, mn1 = 1e30f, mx1 = -1e30f;

#pragma unroll
    for (int k = 0; k < 4; ++k) {
        const int n = n0 + k;
        const float invn = 1.0f / fmaxf(sqrtf(aq[k]), 1e-12f);
        const float d0 = 0.5f * (1.0f - a0[k] * invn);
        const float d1 = 0.5f * (1.0f - a1[k] * invn);
        const int lab = d1 < d0;
        distsb[n] = make_float2(d0, d1);
        sLf += (double)lab;
        sD0 += lab ? 0.0 : (double)d0;
        sD1 += lab ? (double)d1 : 0.0;
        if (T == 1) {
            out[OUT_LABELP + (size_t)b * NPTS + n] = (float)lab;
        }
        if (T == 5) {
            const size_t pn = (size_t)b * NPTS + n;
            out[OUT_LABELS + pn] = (float)lab;
            *(float2*)(out + OUT_ONEHOT + pn * 2) = make_float2(lab ? 0.0f : 1.0f, lab ? 1.0f : 0.0f);
            mn0 = fminf(mn0, d0); mx0 = fmaxf(mx0, d0);
            mn1 = fminf(mn1, d1); mx1 = fmaxf(mx1, d1);
        }
    }

#pragma unroll
    for (int o = 32; o > 0; o >>= 1) {
        sLf += __shfl_down(sLf, o);
        sD0 += __shfl_down(sD0, o);
        sD1 += __shfl_down(sD1, o);
    }
    if (lane == 0) { redd[0][wid] = sLf; redd[1][wid] = sD0; redd[2][wid] = sD1; }
    if (T == 5) {
#pragma unroll
        for (int o = 32; o > 0; o >>= 1) {
            mn0 = fminf(mn0, __shfl_down(mn0, o));
            mx0 = fmaxf(mx0, __shfl_down(mx0, o));
            mn1 = fminf(mn1, __shfl_down(mn1, o));
            mx1 = fmaxf(mx1, __shfl_down(mx1, o));
        }
        if (lane == 0) { redmm[0][wid] = mn0; redmm[1][wid] = mx0; redmm[2][wid] = mn1; redmm[3][wid] = mx1; }
    }
    __syncthreads();
    if (tid == 0) {
        double* pA = (double*)(ws + WS_PA) + (size_t)(b * NBLKA + blk) * 4;
        double t0 = 0, t1 = 0, t2 = 0;
#pragma unroll
        for (int w = 0; w < 8; ++w) { t0 += redd[0][w]; t1 += redd[1][w]; t2 += redd[2][w]; }
        pA[0] = t0; pA[1] = t1; pA[2] = t2;
        if (T == 5) {
            float* pMM = (float*)(ws + WS_PMM) + (size_t)(b * NBLKA + blk) * 4;
            float m0 = 1e30f, m1 = -1e30f, m2 = 1e30f, m3 = -1e30f;
#pragma unroll
            for (int w = 0; w < 8; ++w) {
                m0 = fminf(m0, redmm[0][w]); m1 = fmaxf(m1, redmm[1][w]);
                m2 = fminf(m2, redmm[2][w]); m3 = fmaxf(m3, redmm[3][w]);
            }
            pMM[0] = m0; pMM[1] = m1; pMM[2] = m2; pMM[3] = m3;
        }
    }
}

// Phase B (iteration T): prolog folds reduceA (thresholds) [+ min/max reduce at T==5],
// then flag build (+ Weight output at T==5) and flag-weighted per-channel sums.
// Phase B decomposition/accumulation is part of the numerical contract — DO NOT change.
// X loads non-temporal (bit-identical values).
template <int T>
__global__ __launch_bounds__(512) void phaseB_k(const float* __restrict__ X,
                                                char* __restrict__ ws,
                                                float* __restrict__ out,
                                                const int* __restrict__ n1p,
                                                const int* __restrict__ n2p) {
    const int b = blockIdx.x / NBLKB, blk = blockIdx.x % NBLKB;
    const int tid = threadIdx.x, wid = tid >> 6, lane = tid & 63;
    const int base = blk * BPTS;

    __shared__ float flgC[BPTS];
    __shared__ float flgU[BPTS];
    __shared__ double redc[2][8];
    __shared__ float thr_s[2];
    __shared__ float mm[4];

    // ---- folded reduceA: thresholds from pA partials (NBLKA per batch) ----
    if (wid == 0) {
        const double* pA = (const double*)(ws + WS_PA) + (size_t)b * NBLKA * 4;
        double sLf = 0.0, sD0 = 0.0, sD1 = 0.0;
        if (lane < NBLKA) {
            sLf = pA[lane * 4 + 0]; sD0 = pA[lane * 4 + 1]; sD1 = pA[lane * 4 + 2];
        }
#pragma unroll
        for (int o = 32; o > 0; o >>= 1) {
            sLf += __shfl_down(sLf, o);
            sD0 += __shfl_down(sD0, o);
            sD1 += __shfl_down(sD1, o);
        }
        if (lane == 0) {
            const float fn1 = (float)(*n1p), fn2 = (float)(*n2p);
            const double chgNum = sLf + 1.0;
            const double unchgNum = ((double)NPTS - sLf) + 1.0;
            thr_s[0] = (float)(sD0 / unchgNum) * fn2;   // unchg threshold
            thr_s[1] = (float)(sD1 / chgNum) / fn1;     // chg threshold
        }
    }
    if (T == 5 && wid == 1) {   // global min/max for Weight
        const float* pMM = (const float*)(ws + WS_PMM) + (size_t)b * NBLKA * 4;
        float mn0 = 1e30f, mx0 = -1e30f, mn1 = 1e30f, mx1 = -1e30f;
        if (lane < NBLKA) {
            const float4 v = *(const float4*)(pMM + lane * 4);
            mn0 = v.x; mx0 = v.y; mn1 = v.z; mx1 = v.w;
        }
#pragma unroll
        for (int o = 32; o > 0; o >>= 1) {
            mn0 = fminf(mn0, __shfl_down(mn0, o)); mx0 = fmaxf(mx0, __shfl_down(mx0, o));
            mn1 = fminf(mn1, __shfl_down(mn1, o)); mx1 = fmaxf(mx1, __shfl_down(mx1, o));
        }
        if (lane == 0) { mm[0] = mn0; mm[1] = mx0; mm[2] = mn1; mm[3] = mx1; }
    }
    __syncthreads();

    const float unchgT = thr_s[0], chgT = thr_s[1];
    const float2* distsb = (const float2*)(out + OUT_DISTS) + (size_t)b * NPTS + base;

    float cc = 0.f, cu = 0.f;
#pragma unroll
    for (int i = 0; i < BPTS / 512; ++i) {
        const int nl = tid + 512 * i;
        const float2 d = distsb[nl];
        const int lab = d.y < d.x;
        const float fc = (lab && d.y <= chgT) ? 1.f : 0.f;
        const float fu = (!lab && d.x <= unchgT) ? 1.f : 0.f;
        flgC[nl] = fc;
        flgU[nl] = fu;
        cc += fc; cu += fu;
        if (T == 5) {   // fold Weight output into this read of dists
            const float den0 = mm[1] - mm[0] + 1e-7f;
            const float den1 = mm[3] - mm[2] + 1e-7f;
            float* wout = out + OUT_WEIGHT + ((size_t)b * NPTS + base + nl) * 2;
            *(float2*)wout = make_float2(1.0f - (d.x - mm[0]) / den0,
                                         1.0f - (d.y - mm[2]) / den1);
        }
    }
    double dcc = (double)cc, dcu = (double)cu;
#pragma unroll
    for (int o = 32; o > 0; o >>= 1) {
        dcc += __shfl_down(dcc, o);
        dcu += __shfl_down(dcu, o);
    }
    if (lane == 0) { redc[0][wid] = dcu; redc[1][wid] = dcc; }
    __syncthreads();

    double* pB = (double*)(ws + WS_PB) + (size_t)(b * NBLKB + blk) * PB_STRIDE;
    if (tid == 0) {
        double tu = 0, tc = 0;
#pragma unroll
        for (int w = 0; w < 8; ++w) { tu += redc[0][w]; tc += redc[1][w]; }
        pB[2 * CH + 0] = tu;
        pB[2 * CH + 1] = tc;
    }

    const float* Xb = X + (size_t)b * CH * NPTS + base;
    for (int c0 = CH / 8 - 1; c0 >= 0; --c0) {   // 16 channels per wave, DESCENDING
        const int c = wid * (CH / 8) + c0;
        const float* Xc = Xb + (size_t)c * NPTS;
        float aC = 0.f, aU = 0.f;
#pragma unroll
        for (int it = 0; it < BPTS / 256; ++it) {
            const int idx = it * 256 + lane * 4;
            const fvec4 x = __builtin_nontemporal_load((const fvec4*)(Xc + idx));
            const float4 fc = *(const float4*)(&flgC[idx]);
            const float4 fu = *(const float4*)(&flgU[idx]);
            aC += x.x * fc.x + x.y * fc.y + x.z * fc.z + x.w * fc.w;
            aU += x.x * fu.x + x.y * fu.y + x.z * fu.z + x.w * fu.w;
        }
#pragma unroll
        for (int o = 32; o > 0; o >>= 1) {
            aC += __shfl_down(aC, o);
            aU += __shfl_down(aU, o);
        }
        if (lane == 0) {
            pB[0 * CH + c] = (double)aU;   // row 0 = unchg
            pB[1 * CH + c] = (double)aC;   // row 1 = chg
        }
    }
}

// Final tiny kernel: centersIterout (mean over batches of reduceB(5)) + Cinidist
__global__ __launch_bounds__(256) void finalK(char* __restrict__ ws, float* __restrict__ out) {
    const int tid = threadIdx.x;
    __shared__ float cnt_s[BATCH][2];
    const double* pB0 = (const double*)(ws + WS_PB);
    if (tid < 16) {
        const int bb = tid >> 1, jj = tid & 1;
        double v = 0.0;
        for (int kb = 0; kb < NBLKB; ++kb)
            v += pB0[(size_t)bb * NBLKB * PB_STRIDE + (size_t)kb * PB_STRIDE + 2 * CH + jj];
        cnt_s[bb][jj] = (float)v;
    }
    __syncthreads();
    const int j = tid >> 7;
    double acc = 0.0;
    for (int bb = 0; bb < BATCH; ++bb) {
        double s = 0.0;
        for (int kb = 0; kb < NBLKB; ++kb)
            s += pB0[(size_t)bb * NBLKB * PB_STRIDE + (size_t)kb * PB_STRIDE + tid];
        acc += (double)((float)s / (cnt_s[bb][j] + 1.0f));
    }
    out[OUT_CITER + tid] = (float)(acc / (double)BATCH);
    if (tid == 0) {
        const float* cini = (const float*)(ws + WS_CINI);
        out[OUT_CINID] = (cini[(BATCH - 1) * 2 + 0] + cini[(BATCH - 1) * 2 + 1]) / (float)BATCH;
    }
}

extern "C" void kernel_launch(void* const* d_in, const int* in_sizes, int n_in,
                              void* d_out, int out_size, void* d_ws, size_t ws_size,
                              hipStream_t stream) {
    const float* X = (const float*)d_in[0];       // [8,128,256,256] f32
    const float* cinit = (const float*)d_in[1];   // [2,128] f32
    const int* num1 = (const int*)d_in[2];
    const int* num2 = (const int*)d_in[3];
    float* out = (float*)d_out;
    char* ws = (char*)d_ws;

    const dim3 gA(BATCH * NBLKA), bA(512);
    const dim3 gB(BATCH * NBLKB), bB(512);

    phaseA_k<0><<<gA, bA, 0, stream>>>(X, cinit, ws, out);
    phaseB_k<0><<<gB, bB, 0, stream>>>(X, ws, out, num1, num2);
    phaseA_k<1><<<gA, bA, 0, stream>>>(X, cinit, ws, out);
    phaseB_k<1><<<gB, bB, 0, stream>>>(X, ws, out, num1, num2);
    phaseA_k<2><<<gA, bA, 0, stream>>>(X, cinit, ws, out);
    phaseB_k<2><<<gB, bB, 0, stream>>>(X, ws, out, num1, num2);
    phaseA_k<3><<<gA, bA, 0, stream>>>(X, cinit, ws, out);
    phaseB_k<3><<<gB, bB, 0, stream>>>(X, ws, out, num1, num2);
    phaseA_k<4><<<gA, bA, 0, stream>>>(X, cinit, ws, out);
    phaseB_k<4><<<gB, bB, 0, stream>>>(X, ws, out, num1, num2);
    phaseA_k<5><<<gA, bA, 0, stream>>>(X, cinit, ws, out);
    phaseB_k<5><<<gB, bB, 0, stream>>>(X, ws, out, num1, num2);
    finalK<<<1, 256, 0, stream>>>(ws, out);
}

// Round 13
// 535.258 us; speedup vs baseline: 1.7276x; 1.0739x over previous
//
#include <hip/hip_runtime.h>
#include <math.h>

#define BATCH 8
#define CH 128
#define NPTS 65536
#define NBLKA 32          // blocks per batch in phase A (2048 pts/block, 512 threads, 4 pts/thread)
#define APTS 2048
#define NBLKB 32          // blocks per batch in phase B (2048 pts/block)
#define BPTS 2048
#define PB_STRIDE 260     // 2*CH sums + 2 counts + pad (doubles)

typedef float fvec4 __attribute__((ext_vector_type(4)));

// ---- workspace byte offsets ----
// centers: two ping-pong slots [2][B][2][CH] f32 (slot = t&1, written by phaseA<t> blk0)
static constexpr size_t WS_CENTERS = 0;
static constexpr size_t WS_CINI    = WS_CENTERS + (size_t)2 * BATCH * 2 * CH * sizeof(float); // [B][2] f32
static constexpr size_t WS_PA      = WS_CINI + 256;                                           // [B][NBLKA][4] f64
static constexpr size_t WS_PMM     = WS_PA + (size_t)BATCH * NBLKA * 4 * sizeof(double);      // [B][NBLKA][4] f32
static constexpr size_t WS_PB      = WS_PMM + (size_t)BATCH * NBLKA * 4 * sizeof(float);      // [B][NBLKB][260] f64

// ---- output float offsets (reference return order) ----
static constexpr size_t OUT_CITER  = 0;                                     // [2][CH]
static constexpr size_t OUT_LABELS = 256;                                   // [B][N]
static constexpr size_t OUT_ONEHOT = OUT_LABELS + (size_t)BATCH * NPTS;     // [B][N][2]
static constexpr size_t OUT_WEIGHT = OUT_ONEHOT + (size_t)BATCH * NPTS * 2; // [B][N][2]
static constexpr size_t OUT_DISTS  = OUT_WEIGHT + (size_t)BATCH * NPTS * 2; // [B][N][2] (scratch each iter; final iter = output)
static constexpr size_t OUT_LABELP = OUT_DISTS + (size_t)BATCH * NPTS * 2;  // [B][N]
static constexpr size_t OUT_CINID  = OUT_LABELP + (size_t)BATCH * NPTS;     // scalar

// Phase A (iteration T=0..5): prolog derives centers(T) (T>=1: redundant reduceB fold),
// then computes dists + threshold partial sums. T==1 writes labelPinit; T==5 writes
// labels/onehot + min/max partials.
// Geometry: 256 blocks (1/CU — NEVER fewer; round-11 lesson: 128 blocks = half-idle GPU,
// +65 us/pass). 512 threads x 4 pts = 8 KB contiguous per channel visit (round-10 win).
// X loads CACHEABLE — round-12 lesson: __builtin_nontemporal_load cost +3.2 us/pass.
// NOTE: the per-point channel loop MUST stay sequential c=0..127 — per-point accumulation
// order is part of the numerical contract (argmin label flips otherwise; round-6 lesson).
template <int T>
__global__ __launch_bounds__(512) void phaseA_k(const float* __restrict__ X,
                                                const float* __restrict__ cinit,
                                                char* __restrict__ ws,
                                                float* __restrict__ out) {
    const int b = blockIdx.x / NBLKA;
    const int blk = blockIdx.x % NBLKA;
    const int tid = threadIdx.x;
    const int wid = tid >> 6, lane = tid & 63;   // 8 waves

    __shared__ float cn[2][CH];
    __shared__ double redd[3][8];
    __shared__ float redmm[4][8];

    if constexpr (T == 0) {
        // centers(0) = cinit (same for every batch); normalize into LDS
        if (wid < 2) {
            float v0 = cinit[wid * CH + lane];
            float v1 = cinit[wid * CH + lane + 64];
            float ssq = v0 * v0 + v1 * v1;
#pragma unroll
            for (int o = 32; o > 0; o >>= 1) ssq += __shfl_down(ssq, o);
            ssq = __shfl(ssq, 0);
            const float inv = 1.0f / fmaxf(sqrtf(ssq), 1e-12f);
            cn[wid][lane] = v0 * inv;
            cn[wid][lane + 64] = v1 * inv;
        }
    } else {
        // ---- folded reduceB(T-1): pB partials -> centersIter(T-1) -> EMA -> centers(T) ----
        __shared__ float cnt_s[2];
        __shared__ float red4[4];
        const double* pB = (const double*)(ws + WS_PB) + (size_t)b * NBLKB * PB_STRIDE;
        if (tid < 64) {   // counts: lanes 0..31 -> j=0, 32..63 -> j=1
            const int jj = tid >> 5, kb = tid & 31;
            double v = pB[(size_t)kb * PB_STRIDE + 2 * CH + jj];
#pragma unroll
            for (int o = 16; o > 0; o >>= 1) v += __shfl_down(v, o);
            if ((tid & 31) == 0) cnt_s[jj] = (float)v;
        }
        const int j = tid >> 7, c = tid & (CH - 1);
        double s = 0.0;
        if (tid < 256) {
            for (int kb = 0; kb < NBLKB; ++kb) s += pB[(size_t)kb * PB_STRIDE + j * CH + c];
        }
        __syncthreads();
        float ci = 0.f, old = 0.f, cnew = 0.f;
        if (tid < 256) {
            ci = (float)s / (cnt_s[j] + 1.0f);
            old = (T == 1)
                ? cinit[tid]
                : ((const float*)(ws + WS_CENTERS))[(size_t)((T - 1) & 1) * BATCH * 2 * CH + b * 2 * CH + tid];
            cnew = old + 0.1f * (ci - old);
            float ss = cnew * cnew;
#pragma unroll
            for (int o = 32; o > 0; o >>= 1) ss += __shfl_down(ss, o);
            if (lane == 0) red4[wid] = ss;   // waves 0..3
        }
        __syncthreads();
        if (tid < 256) {
            const float nrm = sqrtf(red4[j * 2] + red4[j * 2 + 1]);
            cn[j][c] = cnew / fmaxf(nrm, 1e-12f);
        }
        if constexpr (T == 1) {
            // cinidist: cos_sim(centersIter(0), centers(0)) rows
            __shared__ float rsd[4], rsa[4], rsb[4];
            if (tid < 256) {
                float sd = ci * old, sa = ci * ci, sb = old * old;
#pragma unroll
                for (int o = 32; o > 0; o >>= 1) {
                    sd += __shfl_down(sd, o); sa += __shfl_down(sa, o); sb += __shfl_down(sb, o);
                }
                if (lane == 0) { rsd[wid] = sd; rsa[wid] = sa; rsb[wid] = sb; }
            }
            __syncthreads();
            if (blk == 0 && tid < 2) {
                const float nsd = rsd[tid * 2] + rsd[tid * 2 + 1];
                const float nsa = rsa[tid * 2] + rsa[tid * 2 + 1];
                const float nsb = rsb[tid * 2] + rsb[tid * 2 + 1];
                ((float*)(ws + WS_CINI))[b * 2 + tid] = nsd / fmaxf(sqrtf(nsa) * sqrtf(nsb), 1e-8f);
            }
        }
        if (blk == 0 && tid < 256) {   // persist centers(T) for phaseA<T+1>
            ((float*)(ws + WS_CENTERS))[(size_t)(T & 1) * BATCH * 2 * CH + b * 2 * CH + tid] = cnew;
        }
    }
    __syncthreads();

    // ---- streaming pass: dists + partial sums (sequential c — DO NOT reorder) ----
    const int n0 = blk * APTS + tid * 4;
    const float* Xb = X + (size_t)b * CH * NPTS + n0;
    fvec4 a0 = (fvec4)0.f, a1 = (fvec4)0.f, aq = (fvec4)0.f;
#pragma unroll 8
    for (int c = 0; c < CH; ++c) {
        const fvec4 x = *(const fvec4*)(Xb + (size_t)c * NPTS);
        const float w0 = cn[0][c], w1 = cn[1][c];
        a0 += x * w0;
        a1 += x * w1;
        aq += x * x;
    }

    float2* distsb = (float2*)(out + OUT_DISTS) + (size_t)b * NPTS;
    double sLf = 0.0, sD0 = 0.0, sD1 = 0.0;
    float mn0 = 1e30f, mx0 = -1e30f, mn1 = 1e30f, mx1 = -1e30f;

#pragma unroll
    for (int k = 0; k < 4; ++k) {
        const int n = n0 + k;
        const float invn = 1.0f / fmaxf(sqrtf(aq[k]), 1e-12f);
        const float d0 = 0.5f * (1.0f - a0[k] * invn);
        const float d1 = 0.5f * (1.0f - a1[k] * invn);
        const int lab = d1 < d0;
        distsb[n] = make_float2(d0, d1);
        sLf += (double)lab;
        sD0 += lab ? 0.0 : (double)d0;
        sD1 += lab ? (double)d1 : 0.0;
        if (T == 1) {
            out[OUT_LABELP + (size_t)b * NPTS + n] = (float)lab;
        }
        if (T == 5) {
            const size_t pn = (size_t)b * NPTS + n;
            out[OUT_LABELS + pn] = (float)lab;
            *(float2*)(out + OUT_ONEHOT + pn * 2) = make_float2(lab ? 0.0f : 1.0f, lab ? 1.0f : 0.0f);
            mn0 = fminf(mn0, d0); mx0 = fmaxf(mx0, d0);
            mn1 = fminf(mn1, d1); mx1 = fmaxf(mx1, d1);
        }
    }

#pragma unroll
    for (int o = 32; o > 0; o >>= 1) {
        sLf += __shfl_down(sLf, o);
        sD0 += __shfl_down(sD0, o);
        sD1 += __shfl_down(sD1, o);
    }
    if (lane == 0) { redd[0][wid] = sLf; redd[1][wid] = sD0; redd[2][wid] = sD1; }
    if (T == 5) {
#pragma unroll
        for (int o = 32; o > 0; o >>= 1) {
            mn0 = fminf(mn0, __shfl_down(mn0, o));
            mx0 = fmaxf(mx0, __shfl_down(mx0, o));
            mn1 = fminf(mn1, __shfl_down(mn1, o));
            mx1 = fmaxf(mx1, __shfl_down(mx1, o));
        }
        if (lane == 0) { redmm[0][wid] = mn0; redmm[1][wid] = mx0; redmm[2][wid] = mn1; redmm[3][wid] = mx1; }
    }
    __syncthreads();
    if (tid == 0) {
        double* pA = (double*)(ws + WS_PA) + (size_t)(b * NBLKA + blk) * 4;
        double t0 = 0, t1 = 0, t2 = 0;
#pragma unroll
        for (int w = 0; w < 8; ++w) { t0 += redd[0][w]; t1 += redd[1][w]; t2 += redd[2][w]; }
        pA[0] = t0; pA[1] = t1; pA[2] = t2;
        if (T == 5) {
            float* pMM = (float*)(ws + WS_PMM) + (size_t)(b * NBLKA + blk) * 4;
            float m0 = 1e30f, m1 = -1e30f, m2 = 1e30f, m3 = -1e30f;
#pragma unroll
            for (int w = 0; w < 8; ++w) {
                m0 = fminf(m0, redmm[0][w]); m1 = fmaxf(m1, redmm[1][w]);
                m2 = fminf(m2, redmm[2][w]); m3 = fmaxf(m3, redmm[3][w]);
            }
            pMM[0] = m0; pMM[1] = m1; pMM[2] = m2; pMM[3] = m3;
        }
    }
}

// Phase B (iteration T): prolog folds reduceA (thresholds) [+ min/max reduce at T==5],
// then flag build (+ Weight output at T==5) and flag-weighted per-channel sums.
// Phase B decomposition/accumulation is part of the numerical contract — DO NOT change.
// X loads cacheable (round-12 lesson: nt loads regress).
template <int T>
__global__ __launch_bounds__(512) void phaseB_k(const float* __restrict__ X,
                                                char* __restrict__ ws,
                                                float* __restrict__ out,
                                                const int* __restrict__ n1p,
                                                const int* __restrict__ n2p) {
    const int b = blockIdx.x / NBLKB, blk = blockIdx.x % NBLKB;
    const int tid = threadIdx.x, wid = tid >> 6, lane = tid & 63;
    const int base = blk * BPTS;

    __shared__ float flgC[BPTS];
    __shared__ float flgU[BPTS];
    __shared__ double redc[2][8];
    __shared__ float thr_s[2];
    __shared__ float mm[4];

    // ---- folded reduceA: thresholds from pA partials (NBLKA per batch) ----
    if (wid == 0) {
        const double* pA = (const double*)(ws + WS_PA) + (size_t)b * NBLKA * 4;
        double sLf = 0.0, sD0 = 0.0, sD1 = 0.0;
        if (lane < NBLKA) {
            sLf = pA[lane * 4 + 0]; sD0 = pA[lane * 4 + 1]; sD1 = pA[lane * 4 + 2];
        }
#pragma unroll
        for (int o = 32; o > 0; o >>= 1) {
            sLf += __shfl_down(sLf, o);
            sD0 += __shfl_down(sD0, o);
            sD1 += __shfl_down(sD1, o);
        }
        if (lane == 0) {
            const float fn1 = (float)(*n1p), fn2 = (float)(*n2p);
            const double chgNum = sLf + 1.0;
            const double unchgNum = ((double)NPTS - sLf) + 1.0;
            thr_s[0] = (float)(sD0 / unchgNum) * fn2;   // unchg threshold
            thr_s[1] = (float)(sD1 / chgNum) / fn1;     // chg threshold
        }
    }
    if (T == 5 && wid == 1) {   // global min/max for Weight
        const float* pMM = (const float*)(ws + WS_PMM) + (size_t)b * NBLKA * 4;
        float mn0 = 1e30f, mx0 = -1e30f, mn1 = 1e30f, mx1 = -1e30f;
        if (lane < NBLKA) {
            const float4 v = *(const float4*)(pMM + lane * 4);
            mn0 = v.x; mx0 = v.y; mn1 = v.z; mx1 = v.w;
        }
#pragma unroll
        for (int o = 32; o > 0; o >>= 1) {
            mn0 = fminf(mn0, __shfl_down(mn0, o)); mx0 = fmaxf(mx0, __shfl_down(mx0, o));
            mn1 = fminf(mn1, __shfl_down(mn1, o)); mx1 = fmaxf(mx1, __shfl_down(mx1, o));
        }
        if (lane == 0) { mm[0] = mn0; mm[1] = mx0; mm[2] = mn1; mm[3] = mx1; }
    }
    __syncthreads();

    const float unchgT = thr_s[0], chgT = thr_s[1];
    const float2* distsb = (const float2*)(out + OUT_DISTS) + (size_t)b * NPTS + base;

    float cc = 0.f, cu = 0.f;
#pragma unroll
    for (int i = 0; i < BPTS / 512; ++i) {
        const int nl = tid + 512 * i;
        const float2 d = distsb[nl];
        const int lab = d.y < d.x;
        const float fc = (lab && d.y <= chgT) ? 1.f : 0.f;
        const float fu = (!lab && d.x <= unchgT) ? 1.f : 0.f;
        flgC[nl] = fc;
        flgU[nl] = fu;
        cc += fc; cu += fu;
        if (T == 5) {   // fold Weight output into this read of dists
            const float den0 = mm[1] - mm[0] + 1e-7f;
            const float den1 = mm[3] - mm[2] + 1e-7f;
            float* wout = out + OUT_WEIGHT + ((size_t)b * NPTS + base + nl) * 2;
            *(float2*)wout = make_float2(1.0f - (d.x - mm[0]) / den0,
                                         1.0f - (d.y - mm[2]) / den1);
        }
    }
    double dcc = (double)cc, dcu = (double)cu;
#pragma unroll
    for (int o = 32; o > 0; o >>= 1) {
        dcc += __shfl_down(dcc, o);
        dcu += __shfl_down(dcu, o);
    }
    if (lane == 0) { redc[0][wid] = dcu; redc[1][wid] = dcc; }
    __syncthreads();

    double* pB = (double*)(ws + WS_PB) + (size_t)(b * NBLKB + blk) * PB_STRIDE;
    if (tid == 0) {
        double tu = 0, tc = 0;
#pragma unroll
        for (int w = 0; w < 8; ++w) { tu += redc[0][w]; tc += redc[1][w]; }
        pB[2 * CH + 0] = tu;
        pB[2 * CH + 1] = tc;
    }

    const float* Xb = X + (size_t)b * CH * NPTS + base;
    for (int c0 = CH / 8 - 1; c0 >= 0; --c0) {   // 16 channels per wave, DESCENDING
        const int c = wid * (CH / 8) + c0;
        const float* Xc = Xb + (size_t)c * NPTS;
        float aC = 0.f, aU = 0.f;
#pragma unroll
        for (int it = 0; it < BPTS / 256; ++it) {
            const int idx = it * 256 + lane * 4;
            const float4 x = *(const float4*)(Xc + idx);
            const float4 fc = *(const float4*)(&flgC[idx]);
            const float4 fu = *(const float4*)(&flgU[idx]);
            aC += x.x * fc.x + x.y * fc.y + x.z * fc.z + x.w * fc.w;
            aU += x.x * fu.x + x.y * fu.y + x.z * fu.z + x.w * fu.w;
        }
#pragma unroll
        for (int o = 32; o > 0; o >>= 1) {
            aC += __shfl_down(aC, o);
            aU += __shfl_down(aU, o);
        }
        if (lane == 0) {
            pB[0 * CH + c] = (double)aU;   // row 0 = unchg
            pB[1 * CH + c] = (double)aC;   // row 1 = chg
        }
    }
}

// Final tiny kernel: centersIterout (mean over batches of reduceB(5)) + Cinidist
__global__ __launch_bounds__(256) void finalK(char* __restrict__ ws, float* __restrict__ out) {
    const int tid = threadIdx.x;
    __shared__ float cnt_s[BATCH][2];
    const double* pB0 = (const double*)(ws + WS_PB);
    if (tid < 16) {
        const int bb = tid >> 1, jj = tid & 1;
        double v = 0.0;
        for (int kb = 0; kb < NBLKB; ++kb)
            v += pB0[(size_t)bb * NBLKB * PB_STRIDE + (size_t)kb * PB_STRIDE + 2 * CH + jj];
        cnt_s[bb][jj] = (float)v;
    }
    __syncthreads();
    const int j = tid >> 7;
    double acc = 0.0;
    for (int bb = 0; bb < BATCH; ++bb) {
        double s = 0.0;
        for (int kb = 0; kb < NBLKB; ++kb)
            s += pB0[(size_t)bb * NBLKB * PB_STRIDE + (size_t)kb * PB_STRIDE + tid];
        acc += (double)((float)s / (cnt_s[bb][j] + 1.0f));
    }
    out[OUT_CITER + tid] = (float)(acc / (double)BATCH);
    if (tid == 0) {
        const float* cini = (const float*)(ws + WS_CINI);
        out[OUT_CINID] = (cini[(BATCH - 1) * 2 + 0] + cini[(BATCH - 1) * 2 + 1]) / (float)BATCH;
    }
}

extern "C" void kernel_launch(void* const* d_in, const int* in_sizes, int n_in,
                              void* d_out, int out_size, void* d_ws, size_t ws_size,
                              hipStream_t stream) {
    const float* X = (const float*)d_in[0];       // [8,128,256,256] f32
    const float* cinit = (const float*)d_in[1];   // [2,128] f32
    const int* num1 = (const int*)d_in[2];
    const int* num2 = (const int*)d_in[3];
    float* out = (float*)d_out;
    char* ws = (char*)d_ws;

    const dim3 gA(BATCH * NBLKA), bA(512);
    const dim3 gB(BATCH * NBLKB), bB(512);

    phaseA_k<0><<<gA, bA, 0, stream>>>(X, cinit, ws, out);
    phaseB_k<0><<<gB, bB, 0, stream>>>(X, ws, out, num1, num2);
    phaseA_k<1><<<gA, bA, 0, stream>>>(X, cinit, ws, out);
    phaseB_k<1><<<gB, bB, 0, stream>>>(X, ws, out, num1, num2);
    phaseA_k<2><<<gA, bA, 0, stream>>>(X, cinit, ws, out);
    phaseB_k<2><<<gB, bB, 0, stream>>>(X, ws, out, num1, num2);
    phaseA_k<3><<<gA, bA, 0, stream>>>(X, cinit, ws, out);
    phaseB_k<3><<<gB, bB, 0, stream>>>(X, ws, out, num1, num2);
    phaseA_k<4><<<gA, bA, 0, stream>>>(X, cinit, ws, out);
    phaseB_k<4><<<gB, bB, 0, stream>>>(X, ws, out, num1, num2);
    phaseA_k<5><<<gA, bA, 0, stream>>>(X, cinit, ws, out);
    phaseB_k<5><<<gB, bB, 0, stream>>>(X, ws, out, num1, num2);
    finalK<<<1, 256, 0, stream>>>(ws, out);
}